// Round 1
// 344.541 us; speedup vs baseline: 1.2155x; 1.2155x over previous
//
#include <hip/hip_runtime.h>

typedef short  short8   __attribute__((ext_vector_type(8)));
typedef float  floatx4  __attribute__((ext_vector_type(4)));
typedef unsigned int uintx2 __attribute__((ext_vector_type(2)));

#define LOG2E_X2 2.8853900817779268f

__device__ __forceinline__ float tanh_fast(float a) {
    // tanh(a) = 1 - 2/(exp(2a)+1)
    float e = __builtin_amdgcn_exp2f(a * LOG2E_X2);
    return 1.0f - 2.0f * __builtin_amdgcn_rcpf(1.0f + e);
}

__device__ __forceinline__ unsigned short bf16rne(float f) {   // setup only
    unsigned u = __float_as_uint(f);
    u += 0x7FFFu + ((u >> 16) & 1u);
    return (unsigned short)(u >> 16);
}

// RNE-pack two f32 -> dword of 2 bf16 (lo=a, hi=b).
#if __has_builtin(__builtin_amdgcn_cvt_pk_bf16_f32)
__device__ __forceinline__ unsigned pk2(float a, float b) {
    auto r = __builtin_amdgcn_cvt_pk_bf16_f32(a, b);   // D.lo=cvt(S0), D.hi=cvt(S1)
    unsigned u; __builtin_memcpy(&u, &r, 4);
    return u;
}
#else
__device__ __forceinline__ unsigned pk2(float a, float b) {
    unsigned r;
    asm("v_cvt_pk_bf16_f32 %0, %1, %2" : "=v"(r) : "v"(a), "v"(b));
    return r;
}
#endif

// 512 blocks x 256 threads; block owns 64 ODE rows for all 64 MLP evals.
// Round 4: dual-stream software pipeline. Rows split into stream A (rows 0-31,
// rt 0-1) and stream B (rows 32-63, rt 2-3), phase-shifted by half a substep.
// Each barrier interval = GEMM2(one stream) + GEMM1(other stream): independent
// MFMA + tanh/epilogue VALU co-scheduled in the same wave. Same barriers/substep
// as before, same per-row arithmetic (bit-identical output expected).
__global__ __launch_bounds__(256, 2) void ode_mfma(
    const float* __restrict__ s_in,  const float* __restrict__ t_in,
    const float* __restrict__ phi_in,const float* __restrict__ bfr_in,
    const float* __restrict__ w1_in, const float* __restrict__ b1_in,
    const float* __restrict__ w2_in, const float* __restrict__ b2_in,
    float* __restrict__ out)
{
    const int tid  = threadIdx.x;
    const int wv   = tid >> 6;
    const int lane = tid & 63;
    const int l15  = lane & 15;
    const int q    = lane >> 4;
    const int wg   = blockIdx.x;
    const int sb   = wg >> 5;
    const int n0   = (wg & 31) << 6;
    const int rowg0 = sb * 2048 + n0;

    __shared__ __align__(16) unsigned short Atile[64][104];
    __shared__ __align__(16) unsigned short Hs[64][264];
    __shared__ __align__(16) float b1s[256];
    __shared__ float dls[8];

    const int d0 = wv * 16 + q * 4;    // lane's 4 consecutive d columns

    // ---- persistent register fragments ----
    short8 w1f[4][3];
#pragma unroll
    for (int ht = 0; ht < 4; ++ht)
#pragma unroll
        for (int kk = 0; kk < 3; ++kk) {
            short8 f;
#pragma unroll
            for (int j = 0; j < 8; ++j) {
                int k = kk * 32 + q * 8 + j;
                int hc = (wv * 4 + ht) * 16 + l15;
                f[j] = (short)bf16rne(w1_in[k * 256 + hc]);
            }
            w1f[ht][kk] = f;
        }
    short8 w2f[8];
#pragma unroll
    for (int kk = 0; kk < 8; ++kk) {
        short8 f;
#pragma unroll
        for (int j = 0; j < 8; ++j) {
            int k = kk * 32 + q * 8 + j;
            f[j] = (short)bf16rne(w2_in[k * 64 + wv * 16 + l15]);
        }
        w2f[kk] = f;
    }

    // RK4 state: lane owns (row = rt*16+l15, d = d0..d0+3); rt 0-1 = stream A,
    // rt 2-3 = stream B.
    floatx4 xv[4], kacc[4], fbv[4];
    {
        const floatx4 b2v = *(const floatx4*)(b2_in + d0);
#pragma unroll
        for (int rt = 0; rt < 4; ++rt) {
            int rg = rowg0 + rt * 16 + l15;
            xv[rt]  = *(const floatx4*)(s_in   + rg * 64 + d0);
            fbv[rt] = b2v + *(const floatx4*)(bfr_in + rg * 64 + d0);
            uintx2 px = { pk2(xv[rt][0], xv[rt][1]), pk2(xv[rt][2], xv[rt][3]) };
            *(uintx2*)&Atile[rt * 16 + l15][d0] = px;
        }
    }
    // Phi -> Atile cols 64..95
#pragma unroll
    for (int it = 0; it < 2; ++it) {
        int c2 = tid * 2 + it;           // 0..511
        int row = c2 >> 3, cc = c2 & 7;
        floatx4 p = *(const floatx4*)(phi_in + (rowg0 + row) * 32 + cc * 4);
        uintx2 px = { pk2(p[0], p[1]), pk2(p[2], p[3]) };
        *(uintx2*)&Atile[row][64 + cc * 4] = px;
    }
    if (tid < 64) *(floatx4*)&b1s[tid * 4] = *(const floatx4*)(b1_in + tid * 4);
    if (tid < 8)  dls[tid] = t_in[sb * 9 + tid + 1] - t_in[sb * 9 + tid];

    __syncthreads();

// ---- GEMM1 for one stream (row-tiles RT0, RT0+1): X -> tanh -> Hs ----
#define DO_G1(RT0)                                                              \
    {                                                                           \
        floatx4 bbf[4];                                                         \
        _Pragma("unroll")                                                       \
        for (int ht = 0; ht < 4; ++ht)                                          \
            bbf[ht] = *(const floatx4*)&b1s[(wv * 4 + ht) * 16 + q * 4];        \
        floatx4 acc1[4][2];                                                     \
        {                                                                       \
            short8 xb[2];                                                       \
            _Pragma("unroll")                                                   \
            for (int r2 = 0; r2 < 2; ++r2)                                      \
                xb[r2] = *(const short8*)&Atile[(RT0 + r2) * 16 + l15][q * 8];  \
            _Pragma("unroll")                                                   \
            for (int ht = 0; ht < 4; ++ht)                                      \
                _Pragma("unroll")                                               \
                for (int r2 = 0; r2 < 2; ++r2)                                  \
                    acc1[ht][r2] = __builtin_amdgcn_mfma_f32_16x16x32_bf16(     \
                        w1f[ht][0], xb[r2], bbf[ht], 0, 0, 0);                  \
        }                                                                       \
        _Pragma("unroll")                                                       \
        for (int kk = 1; kk < 3; ++kk) {                                        \
            short8 xb[2];                                                       \
            _Pragma("unroll")                                                   \
            for (int r2 = 0; r2 < 2; ++r2)                                      \
                xb[r2] = *(const short8*)&Atile[(RT0 + r2) * 16 + l15][kk * 32 + q * 8]; \
            _Pragma("unroll")                                                   \
            for (int ht = 0; ht < 4; ++ht)                                      \
                _Pragma("unroll")                                               \
                for (int r2 = 0; r2 < 2; ++r2)                                  \
                    acc1[ht][r2] = __builtin_amdgcn_mfma_f32_16x16x32_bf16(     \
                        w1f[ht][kk], xb[r2], acc1[ht][r2], 0, 0, 0);            \
        }                                                                       \
        _Pragma("unroll")                                                       \
        for (int ht = 0; ht < 4; ++ht)                                          \
            _Pragma("unroll")                                                   \
            for (int r2 = 0; r2 < 2; ++r2) {                                    \
                uintx2 hp = { pk2(tanh_fast(acc1[ht][r2][0]), tanh_fast(acc1[ht][r2][1])), \
                              pk2(tanh_fast(acc1[ht][r2][2]), tanh_fast(acc1[ht][r2][3])) }; \
                *(uintx2*)&Hs[(RT0 + r2) * 16 + l15][(wv * 4 + ht) * 16 + q * 4] = hp; \
            }                                                                   \
    }

// ---- GEMM2 + RK4 epilogue for one stream (row-tiles RT0, RT0+1) ----
#define DO_G2(RT0)                                                              \
    {                                                                           \
        floatx4 acc2[2];                                                        \
        _Pragma("unroll")                                                       \
        for (int r2 = 0; r2 < 2; ++r2) {                                        \
            short8 hb = *(const short8*)&Hs[(RT0 + r2) * 16 + l15][q * 8];      \
            acc2[r2] = __builtin_amdgcn_mfma_f32_16x16x32_bf16(                 \
                w2f[0], hb, fbv[RT0 + r2], 0, 0, 0);                            \
        }                                                                       \
        _Pragma("unroll")                                                       \
        for (int kk = 1; kk < 8; ++kk)                                          \
            _Pragma("unroll")                                                   \
            for (int r2 = 0; r2 < 2; ++r2) {                                    \
                short8 hb = *(const short8*)&Hs[(RT0 + r2) * 16 + l15][kk * 32 + q * 8]; \
                acc2[r2] = __builtin_amdgcn_mfma_f32_16x16x32_bf16(             \
                    w2f[kk], hb, acc2[r2], 0, 0, 0);                            \
            }                                                                   \
        _Pragma("unroll")                                                       \
        for (int r2 = 0; r2 < 2; ++r2) {                                        \
            const int rt = RT0 + r2;                                            \
            floatx4 kv = acc2[r2] * dlt;                                        \
            floatx4 xe;                                                         \
            if (sub == 0)      { kacc[rt] = kv;            xe = xv[rt] + 0.25f * kv; } \
            else if (sub == 1) { kacc[rt] += 2.0f * kv;    xe = xv[rt] + 0.25f * kv; } \
            else if (sub == 2) { kacc[rt] += 2.0f * kv;    xe = xv[rt] + 0.5f  * kv; } \
            else               { xv[rt] += (kacc[rt] + kv) * (1.0f / 12.0f); xe = xv[rt]; } \
            uintx2 px = { pk2(xe[0], xe[1]), pk2(xe[2], xe[3]) };               \
            *(uintx2*)&Atile[rt * 16 + l15][d0] = px;                           \
        }                                                                       \
        if ((i & 7) == 7) {                                                     \
            const int ob = (sb * 8 + (i >> 3)) * 2048;                          \
            _Pragma("unroll")                                                   \
            for (int r2 = 0; r2 < 2; ++r2) {                                    \
                const int rt = RT0 + r2;                                        \
                *(floatx4*)(out + (size_t)(ob + n0 + rt * 16 + l15) * 64 + d0) = xv[rt]; \
            }                                                                   \
        }                                                                       \
    }

    // Prologue: stream A's first GEMM1 (HsA ready for iteration 0).
    DO_G1(0)

    // Steady state: two barrier intervals per iteration, each pairing one
    // stream's GEMM2+epilogue with the other stream's GEMM1+tanh.
#pragma unroll 1
    for (int i = 0; i < 64; ++i) {
        const float dlt = dls[i >> 3];
        const int sub = i & 3;
        __syncthreads();   // HsA(i) + AtileB(i) visible
        DO_G2(0)           // stream A: GEMM2 + epilogue (writes AtileA, maybe out)
        DO_G1(2)           // stream B: GEMM1 + tanh (reads AtileB, writes HsB)
        __syncthreads();   // HsB(i) + AtileA(i+1) visible
        DO_G2(2)           // stream B: GEMM2 + epilogue
        if (i < 63) { DO_G1(0) }   // stream A: GEMM1 of substep i+1
    }
#undef DO_G1
#undef DO_G2
}

extern "C" void kernel_launch(void* const* d_in, const int* in_sizes, int n_in,
                              void* d_out, int out_size, void* d_ws, size_t ws_size,
                              hipStream_t stream) {
    const float* s_in  = (const float*)d_in[0];
    const float* t_in  = (const float*)d_in[1];
    const float* phi   = (const float*)d_in[2];
    const float* bfr   = (const float*)d_in[3];
    const float* w1    = (const float*)d_in[4];
    const float* b1    = (const float*)d_in[5];
    const float* w2    = (const float*)d_in[6];
    const float* b2    = (const float*)d_in[7];
    ode_mfma<<<512, 256, 0, stream>>>(s_in, t_in, phi, bfr, w1, b1, w2, b2, (float*)d_out);
}

// Round 2
// 337.754 us; speedup vs baseline: 1.2399x; 1.0201x over previous
//
#include <hip/hip_runtime.h>

typedef short  short8   __attribute__((ext_vector_type(8)));
typedef float  floatx4  __attribute__((ext_vector_type(4)));
typedef unsigned int uintx2 __attribute__((ext_vector_type(2)));

#define LOG2E_X2 2.8853900817779268f

// Inputs to this tanh are PRE-SCALED by 2*log2(e) (folded into W1/b1 at setup):
// tanh(a) = 1 - 2/(exp2(2a*log2e)+1), y = 2a*log2e already.
__device__ __forceinline__ float tanh_pre(float y) {
    float e = __builtin_amdgcn_exp2f(y);
    return 1.0f - 2.0f * __builtin_amdgcn_rcpf(1.0f + e);
}

__device__ __forceinline__ unsigned short bf16rne(float f) {   // setup only
    unsigned u = __float_as_uint(f);
    u += 0x7FFFu + ((u >> 16) & 1u);
    return (unsigned short)(u >> 16);
}

// RNE-pack two f32 -> dword of 2 bf16 (lo=a, hi=b).
#if __has_builtin(__builtin_amdgcn_cvt_pk_bf16_f32)
__device__ __forceinline__ unsigned pk2(float a, float b) {
    auto r = __builtin_amdgcn_cvt_pk_bf16_f32(a, b);
    unsigned u; __builtin_memcpy(&u, &r, 4);
    return u;
}
#else
__device__ __forceinline__ unsigned pk2(float a, float b) {
    unsigned r;
    asm("v_cvt_pk_bf16_f32 %0, %1, %2" : "=v"(r) : "v"(a), "v"(b));
    return r;
}
#endif

// Round 5: occupancy doubling. 512 blocks x 512 threads (8 waves). Per-wave
// work halved along FREE dims only (no K-split / no reductions):
//   GEMM1: wave w owns 32 h-channels (h in [w*32, w*32+32)), all 64 rows.
//   GEMM2: wave (wv2=w&3, rh=w>>2) owns d-block wv2*16..+16, ONE 16-row tile
//          per stream (rt = rh for stream A, 2+rh for stream B), full K=256.
// 4096 waves total = 4 waves/SIMD (vs 2) -> latency hiding for lgkm/barrier.
// Dual-stream pipeline (A: rows 0-31, B: rows 32-63) unchanged from R4.
// W1/b1 pre-scaled by 2*log2e -> 4-op tanh.
__global__ __launch_bounds__(512, 4) void ode_mfma(
    const float* __restrict__ s_in,  const float* __restrict__ t_in,
    const float* __restrict__ phi_in,const float* __restrict__ bfr_in,
    const float* __restrict__ w1_in, const float* __restrict__ b1_in,
    const float* __restrict__ w2_in, const float* __restrict__ b2_in,
    float* __restrict__ out)
{
    const int tid  = threadIdx.x;
    const int w    = tid >> 6;         // wave 0..7
    const int wv2  = w & 3;            // d-block for GEMM2 / epilogue
    const int rh   = w >> 2;           // row-half for GEMM2 / epilogue
    const int lane = tid & 63;
    const int l15  = lane & 15;
    const int q    = lane >> 4;
    const int wg   = blockIdx.x;
    const int sb   = wg >> 5;
    const int n0   = (wg & 31) << 6;
    const int rowg0 = sb * 2048 + n0;

    __shared__ __align__(16) unsigned short Atile[64][104];
    __shared__ __align__(16) unsigned short Hs[64][264];
    __shared__ __align__(16) float b1s[256];
    __shared__ float dls[8];

    const int d0 = wv2 * 16 + q * 4;   // lane's 4 consecutive d columns

    // ---- persistent register fragments ----
    // W1T fragments: 2 ht blocks of 16 h-channels = wave's 32 channels.
    short8 w1f[2][3];
#pragma unroll
    for (int ht = 0; ht < 2; ++ht)
#pragma unroll
        for (int kk = 0; kk < 3; ++kk) {
            short8 f;
#pragma unroll
            for (int j = 0; j < 8; ++j) {
                int k = kk * 32 + q * 8 + j;
                int hc = w * 32 + ht * 16 + l15;
                f[j] = (short)bf16rne(w1_in[k * 256 + hc] * LOG2E_X2);
            }
            w1f[ht][kk] = f;
        }
    short8 w2f[8];
#pragma unroll
    for (int kk = 0; kk < 8; ++kk) {
        short8 f;
#pragma unroll
        for (int j = 0; j < 8; ++j) {
            int k = kk * 32 + q * 8 + j;
            f[j] = (short)bf16rne(w2_in[k * 64 + wv2 * 16 + l15]);
        }
        w2f[kk] = f;
    }

    // RK4 state: lane owns (row = rt*16+l15, d = d0..d0+3) for its two tiles:
    // si=0 -> rt=rh (stream A), si=1 -> rt=2+rh (stream B).
    floatx4 xv[2], kacc[2], fbv[2];
    {
        const floatx4 b2v = *(const floatx4*)(b2_in + d0);
#pragma unroll
        for (int si = 0; si < 2; ++si) {
            int rt = si * 2 + rh;
            int rg = rowg0 + rt * 16 + l15;
            xv[si]  = *(const floatx4*)(s_in   + rg * 64 + d0);
            fbv[si] = b2v + *(const floatx4*)(bfr_in + rg * 64 + d0);
            uintx2 px = { pk2(xv[si][0], xv[si][1]), pk2(xv[si][2], xv[si][3]) };
            *(uintx2*)&Atile[rt * 16 + l15][d0] = px;
        }
    }
    // Phi -> Atile cols 64..95 (512 threads, one floatx4 each)
    {
        int row = tid >> 3, cc = tid & 7;
        floatx4 p = *(const floatx4*)(phi_in + (rowg0 + row) * 32 + cc * 4);
        uintx2 px = { pk2(p[0], p[1]), pk2(p[2], p[3]) };
        *(uintx2*)&Atile[row][64 + cc * 4] = px;
    }
    if (tid < 64) {
        floatx4 v = *(const floatx4*)(b1_in + tid * 4);
        v *= LOG2E_X2;
        *(floatx4*)&b1s[tid * 4] = v;
    }
    if (tid < 8)  dls[tid] = t_in[sb * 9 + tid + 1] - t_in[sb * 9 + tid];

    __syncthreads();

// ---- GEMM1 for one stream (row-tiles RT0, RT0+1): X -> tanh -> Hs ----
// Wave computes its 32 h-channels for both 16-row tiles of the stream.
#define DO_G1(RT0)                                                              \
    {                                                                           \
        floatx4 acc1[2][2];                                                     \
        {                                                                       \
            short8 xb[2];                                                       \
            _Pragma("unroll")                                                   \
            for (int r2 = 0; r2 < 2; ++r2)                                      \
                xb[r2] = *(const short8*)&Atile[(RT0 + r2) * 16 + l15][q * 8];  \
            _Pragma("unroll")                                                   \
            for (int ht = 0; ht < 2; ++ht) {                                    \
                floatx4 bbf = *(const floatx4*)&b1s[w * 32 + ht * 16 + q * 4];  \
                _Pragma("unroll")                                               \
                for (int r2 = 0; r2 < 2; ++r2)                                  \
                    acc1[ht][r2] = __builtin_amdgcn_mfma_f32_16x16x32_bf16(     \
                        w1f[ht][0], xb[r2], bbf, 0, 0, 0);                      \
            }                                                                   \
        }                                                                       \
        _Pragma("unroll")                                                       \
        for (int kk = 1; kk < 3; ++kk) {                                        \
            short8 xb[2];                                                       \
            _Pragma("unroll")                                                   \
            for (int r2 = 0; r2 < 2; ++r2)                                      \
                xb[r2] = *(const short8*)&Atile[(RT0 + r2) * 16 + l15][kk * 32 + q * 8]; \
            _Pragma("unroll")                                                   \
            for (int ht = 0; ht < 2; ++ht)                                      \
                _Pragma("unroll")                                               \
                for (int r2 = 0; r2 < 2; ++r2)                                  \
                    acc1[ht][r2] = __builtin_amdgcn_mfma_f32_16x16x32_bf16(     \
                        w1f[ht][kk], xb[r2], acc1[ht][r2], 0, 0, 0);            \
        }                                                                       \
        _Pragma("unroll")                                                       \
        for (int ht = 0; ht < 2; ++ht)                                          \
            _Pragma("unroll")                                                   \
            for (int r2 = 0; r2 < 2; ++r2) {                                    \
                uintx2 hp = { pk2(tanh_pre(acc1[ht][r2][0]), tanh_pre(acc1[ht][r2][1])), \
                              pk2(tanh_pre(acc1[ht][r2][2]), tanh_pre(acc1[ht][r2][3])) }; \
                *(uintx2*)&Hs[(RT0 + r2) * 16 + l15][w * 32 + ht * 16 + q * 4] = hp; \
            }                                                                   \
    }

// ---- GEMM2 + RK4 epilogue for one stream; SI = state index (0=A, 1=B).
// Wave handles its single row-tile rt = SI*2+rh, d-block wv2, full K=256.
#define DO_G2(SI)                                                               \
    {                                                                           \
        const int rt = (SI) * 2 + rh;                                           \
        floatx4 acc2;                                                           \
        {                                                                       \
            short8 hb = *(const short8*)&Hs[rt * 16 + l15][q * 8];              \
            acc2 = __builtin_amdgcn_mfma_f32_16x16x32_bf16(                     \
                w2f[0], hb, fbv[SI], 0, 0, 0);                                  \
        }                                                                       \
        _Pragma("unroll")                                                       \
        for (int kk = 1; kk < 8; ++kk) {                                        \
            short8 hb = *(const short8*)&Hs[rt * 16 + l15][kk * 32 + q * 8];    \
            acc2 = __builtin_amdgcn_mfma_f32_16x16x32_bf16(                     \
                w2f[kk], hb, acc2, 0, 0, 0);                                    \
        }                                                                       \
        {                                                                       \
            floatx4 kv = acc2 * dlt;                                            \
            floatx4 xe;                                                         \
            if (sub == 0)      { kacc[SI] = kv;            xe = xv[SI] + 0.25f * kv; } \
            else if (sub == 1) { kacc[SI] += 2.0f * kv;    xe = xv[SI] + 0.25f * kv; } \
            else if (sub == 2) { kacc[SI] += 2.0f * kv;    xe = xv[SI] + 0.5f  * kv; } \
            else               { xv[SI] += (kacc[SI] + kv) * (1.0f / 12.0f); xe = xv[SI]; } \
            uintx2 px = { pk2(xe[0], xe[1]), pk2(xe[2], xe[3]) };               \
            *(uintx2*)&Atile[rt * 16 + l15][d0] = px;                           \
        }                                                                       \
        if ((i & 7) == 7) {                                                     \
            const int ob = (sb * 8 + (i >> 3)) * 2048;                          \
            *(floatx4*)(out + (size_t)(ob + n0 + rt * 16 + l15) * 64 + d0) = xv[SI]; \
        }                                                                       \
    }

    // Prologue: stream A's first GEMM1 (HsA ready for iteration 0).
    DO_G1(0)

    // Steady state: two barrier intervals per iteration, each pairing one
    // stream's GEMM2+epilogue with the other stream's GEMM1+tanh.
#pragma unroll 1
    for (int i = 0; i < 64; ++i) {
        const float dlt = dls[i >> 3];
        const int sub = i & 3;
        __syncthreads();   // HsA(i) + AtileB(i) visible
        DO_G2(0)           // stream A: GEMM2 + epilogue (writes AtileA, maybe out)
        DO_G1(2)           // stream B: GEMM1 + tanh (reads AtileB, writes HsB)
        __syncthreads();   // HsB(i) + AtileA(i+1) visible
        DO_G2(1)           // stream B: GEMM2 + epilogue
        if (i < 63) { DO_G1(0) }   // stream A: GEMM1 of substep i+1
    }
#undef DO_G1
#undef DO_G2
}

extern "C" void kernel_launch(void* const* d_in, const int* in_sizes, int n_in,
                              void* d_out, int out_size, void* d_ws, size_t ws_size,
                              hipStream_t stream) {
    const float* s_in  = (const float*)d_in[0];
    const float* t_in  = (const float*)d_in[1];
    const float* phi   = (const float*)d_in[2];
    const float* bfr   = (const float*)d_in[3];
    const float* w1    = (const float*)d_in[4];
    const float* b1    = (const float*)d_in[5];
    const float* w2    = (const float*)d_in[6];
    const float* b2    = (const float*)d_in[7];
    ode_mfma<<<512, 512, 0, stream>>>(s_in, t_in, phi, bfr, w1, b1, w2, b2, (float*)d_out);
}

// Round 3
// 298.344 us; speedup vs baseline: 1.4037x; 1.1321x over previous
//
#include <hip/hip_runtime.h>

typedef short  short8   __attribute__((ext_vector_type(8)));
typedef float  floatx4  __attribute__((ext_vector_type(4)));
typedef unsigned int uintx2 __attribute__((ext_vector_type(2)));

#define LOG2E_X2 2.8853900817779268f

// Inputs pre-scaled by 2*log2(e) (folded into W1/b1): tanh(a)=1-2/(exp2(y)+1).
__device__ __forceinline__ float tanh_pre(float y) {
    float e = __builtin_amdgcn_exp2f(y);
    return 1.0f - 2.0f * __builtin_amdgcn_rcpf(1.0f + e);
}

__device__ __forceinline__ unsigned short bf16rne(float f) {   // setup only
    unsigned u = __float_as_uint(f);
    u += 0x7FFFu + ((u >> 16) & 1u);
    return (unsigned short)(u >> 16);
}

// RNE-pack two f32 -> dword of 2 bf16 (lo=a, hi=b).
#if __has_builtin(__builtin_amdgcn_cvt_pk_bf16_f32)
__device__ __forceinline__ unsigned pk2(float a, float b) {
    auto r = __builtin_amdgcn_cvt_pk_bf16_f32(a, b);
    unsigned u; __builtin_memcpy(&u, &r, 4);
    return u;
}
#else
__device__ __forceinline__ unsigned pk2(float a, float b) {
    unsigned r;
    asm("v_cvt_pk_bf16_f32 %0, %1, %2" : "=v"(r) : "v"(a), "v"(b));
    return r;
}
#endif

// Unpack 4 bf16 (packed lo/hi per dword) -> floatx4, exact.
__device__ __forceinline__ floatx4 unpk4(uintx2 u) {
    floatx4 r;
    r[0] = __uint_as_float(u.x << 16);
    r[1] = __uint_as_float(u.x & 0xffff0000u);
    r[2] = __uint_as_float(u.y << 16);
    r[3] = __uint_as_float(u.y & 0xffff0000u);
    return r;
}

// Round 6: producer/consumer wave specialization (LDS-issue-bound fix).
// 512 blocks x 512 threads. Waves 0-3 = G1 producers (each: 64 h-channels x
// both row-tiles of a stream; w1f[4][3]); waves 4-7 = G2 consumers (each:
// one 16-row tile x 32 d-columns; w2f[2][8]; own the RK4 state).
// Dual-stream ping-pong: interval1 = G2(A) || G1(B); interval2 = G2(B) || G1(A,i+1).
// LDS b128 reads per substep/block: 224 -> 112. Barrier counts matched on
// both sides of the wave-uniform branch (129 each).
__global__ __launch_bounds__(512, 4) void ode_mfma(
    const float* __restrict__ s_in,  const float* __restrict__ t_in,
    const float* __restrict__ phi_in,const float* __restrict__ bfr_in,
    const float* __restrict__ w1_in, const float* __restrict__ b1_in,
    const float* __restrict__ w2_in, const float* __restrict__ b2_in,
    float* __restrict__ out)
{
    const int tid  = threadIdx.x;
    const int w    = tid >> 6;         // wave 0..7
    const int lane = tid & 63;
    const int l15  = lane & 15;
    const int q    = lane >> 4;
    const int wg   = blockIdx.x;
    const int sb   = wg >> 5;
    const int n0   = (wg & 31) << 6;
    const int rowg0 = sb * 2048 + n0;

    __shared__ __align__(16) unsigned short Atile[64][104];
    __shared__ __align__(16) unsigned short Hs[64][264];
    __shared__ float dls[8];

    // Phi -> Atile cols 64..95 (all 512 threads, one floatx4 each; written once)
    {
        int row = tid >> 3, cc = tid & 7;
        floatx4 p = *(const floatx4*)(phi_in + (rowg0 + row) * 32 + cc * 4);
        uintx2 px = { pk2(p[0], p[1]), pk2(p[2], p[3]) };
        *(uintx2*)&Atile[row][64 + cc * 4] = px;
    }
    if (tid < 8) dls[tid] = t_in[sb * 9 + tid + 1] - t_in[sb * 9 + tid];

// ---- G1 producer: stream row-tiles (RT0, RT0+1), this wave's 64 h-channels.
// Reads Atile, writes Hs[.][hb0..hb0+64). 24 MFMA, 6 ds_read_b128, 8 ds_write_b64.
#define DO_G1(RT0)                                                              \
    {                                                                           \
        floatx4 acc1[4][2];                                                     \
        {                                                                       \
            short8 xb[2];                                                       \
            _Pragma("unroll")                                                   \
            for (int r2 = 0; r2 < 2; ++r2)                                      \
                xb[r2] = *(const short8*)&Atile[(RT0 + r2) * 16 + l15][q * 8];  \
            _Pragma("unroll")                                                   \
            for (int ht = 0; ht < 4; ++ht)                                      \
                _Pragma("unroll")                                               \
                for (int r2 = 0; r2 < 2; ++r2)                                  \
                    acc1[ht][r2] = __builtin_amdgcn_mfma_f32_16x16x32_bf16(     \
                        w1f[ht][0], xb[r2], bbf[ht], 0, 0, 0);                  \
        }                                                                       \
        _Pragma("unroll")                                                       \
        for (int kk = 1; kk < 3; ++kk) {                                        \
            short8 xb[2];                                                       \
            _Pragma("unroll")                                                   \
            for (int r2 = 0; r2 < 2; ++r2)                                      \
                xb[r2] = *(const short8*)&Atile[(RT0 + r2) * 16 + l15][kk * 32 + q * 8]; \
            _Pragma("unroll")                                                   \
            for (int ht = 0; ht < 4; ++ht)                                      \
                _Pragma("unroll")                                               \
                for (int r2 = 0; r2 < 2; ++r2)                                  \
                    acc1[ht][r2] = __builtin_amdgcn_mfma_f32_16x16x32_bf16(     \
                        w1f[ht][kk], xb[r2], acc1[ht][r2], 0, 0, 0);            \
        }                                                                       \
        _Pragma("unroll")                                                       \
        for (int ht = 0; ht < 4; ++ht)                                          \
            _Pragma("unroll")                                                   \
            for (int r2 = 0; r2 < 2; ++r2) {                                    \
                uintx2 hp = { pk2(tanh_pre(acc1[ht][r2][0]), tanh_pre(acc1[ht][r2][1])), \
                              pk2(tanh_pre(acc1[ht][r2][2]), tanh_pre(acc1[ht][r2][3])) }; \
                *(uintx2*)&Hs[(RT0 + r2) * 16 + l15][hb0 + ht * 16 + q * 4] = hp; \
            }                                                                   \
    }

// ---- G2 consumer: stream SI, this wave's tile rt = SI*2+rt_rel, d cols
// dp..dp+32. Reads Hs (8 b128, each feeds 2 MFMA), RK4 epilogue, writes Atile.
#define DO_G2(SI)                                                               \
    {                                                                           \
        const int rt = (SI) * 2 + rt_rel;                                       \
        const unsigned short* hrow = &Hs[rt * 16 + l15][0];                     \
        floatx4 acc2a, acc2b;                                                   \
        {                                                                       \
            short8 hb = *(const short8*)&hrow[q * 8];                           \
            acc2a = __builtin_amdgcn_mfma_f32_16x16x32_bf16(                    \
                w2f[0][0], hb, unpk4(fpk[SI][0]), 0, 0, 0);                     \
            acc2b = __builtin_amdgcn_mfma_f32_16x16x32_bf16(                    \
                w2f[1][0], hb, unpk4(fpk[SI][1]), 0, 0, 0);                     \
        }                                                                       \
        _Pragma("unroll")                                                       \
        for (int kk = 1; kk < 8; ++kk) {                                        \
            short8 hb = *(const short8*)&hrow[kk * 32 + q * 8];                 \
            acc2a = __builtin_amdgcn_mfma_f32_16x16x32_bf16(                    \
                w2f[0][kk], hb, acc2a, 0, 0, 0);                                \
            acc2b = __builtin_amdgcn_mfma_f32_16x16x32_bf16(                    \
                w2f[1][kk], hb, acc2b, 0, 0, 0);                                \
        }                                                                       \
        _Pragma("unroll")                                                       \
        for (int h = 0; h < 2; ++h) {                                           \
            floatx4 kv = (h == 0 ? acc2a : acc2b) * dlt;                        \
            floatx4 xe;                                                         \
            if (sub == 0)      { kacc[SI][h] = kv;            xe = xv[SI][h] + 0.25f * kv; } \
            else if (sub == 1) { kacc[SI][h] += 2.0f * kv;    xe = xv[SI][h] + 0.25f * kv; } \
            else if (sub == 2) { kacc[SI][h] += 2.0f * kv;    xe = xv[SI][h] + 0.5f  * kv; } \
            else               { xv[SI][h] += (kacc[SI][h] + kv) * (1.0f / 12.0f); xe = xv[SI][h]; } \
            uintx2 px = { pk2(xe[0], xe[1]), pk2(xe[2], xe[3]) };               \
            *(uintx2*)&Atile[rt * 16 + l15][dp + h * 16 + q * 4] = px;          \
        }                                                                       \
        if (ii == 7) {                                                          \
            const size_t ob = (size_t)((sb * 8 + blk) * 2048 + n0 + rt * 16 + l15) * 64; \
            _Pragma("unroll")                                                   \
            for (int h = 0; h < 2; ++h)                                         \
                *(floatx4*)(out + ob + dp + h * 16 + q * 4) = xv[SI][h];        \
        }                                                                       \
    }

    if (w < 4) {
        // ================= G1 producer waves =================
        const int hb0 = w * 64;
        short8 w1f[4][3];
#pragma unroll
        for (int ht = 0; ht < 4; ++ht)
#pragma unroll
            for (int kk = 0; kk < 3; ++kk) {
                short8 f;
#pragma unroll
                for (int j = 0; j < 8; ++j) {
                    int k = kk * 32 + q * 8 + j;
                    int hc = hb0 + ht * 16 + l15;
                    f[j] = (short)bf16rne(w1_in[k * 256 + hc] * LOG2E_X2);
                }
                w1f[ht][kk] = f;
            }
        floatx4 bbf[4];
#pragma unroll
        for (int ht = 0; ht < 4; ++ht) {
            floatx4 v = *(const floatx4*)(b1_in + hb0 + ht * 16 + q * 4);
            bbf[ht] = v * LOG2E_X2;
        }

        __syncthreads();                 // barrier #1: Atile init + Phi ready
        DO_G1(0)                         // prologue: HsA(0)
#pragma unroll 1
        for (int it = 0; it < 64; ++it) {
            __syncthreads();             // HsA(it)/AtileB(it) published
            DO_G1(2)                     // stream B, substep it
            __syncthreads();             // HsB(it)/AtileA(it+1) published
            if (it < 63) { DO_G1(0) }    // stream A, substep it+1
        }
    } else {
        // ================= G2 consumer waves =================
        const int g = w - 4;
        const int rt_rel = g >> 1;
        const int dp = (g & 1) * 32;
        short8 w2f[2][8];                // [d-half][kk]
#pragma unroll
        for (int h = 0; h < 2; ++h)
#pragma unroll
            for (int kk = 0; kk < 8; ++kk) {
                short8 f;
#pragma unroll
                for (int j = 0; j < 8; ++j) {
                    int k = kk * 32 + q * 8 + j;
                    f[j] = (short)bf16rne(w2_in[k * 64 + dp + h * 16 + l15]);
                }
                w2f[h][kk] = f;
            }

        floatx4 xv[2][2], kacc[2][2];
        uintx2 fpk[2][2];                // b2+bfr, bf16-packed C-seeds
#pragma unroll
        for (int si = 0; si < 2; ++si) {
            const int rt = si * 2 + rt_rel;
            const int rg = rowg0 + rt * 16 + l15;
#pragma unroll
            for (int h = 0; h < 2; ++h) {
                const int dh = dp + h * 16 + q * 4;
                xv[si][h] = *(const floatx4*)(s_in + rg * 64 + dh);
                floatx4 fb = *(const floatx4*)(b2_in + dh)
                           + *(const floatx4*)(bfr_in + rg * 64 + dh);
                fpk[si][h] = (uintx2){ pk2(fb[0], fb[1]), pk2(fb[2], fb[3]) };
                uintx2 px = { pk2(xv[si][h][0], xv[si][h][1]),
                              pk2(xv[si][h][2], xv[si][h][3]) };
                *(uintx2*)&Atile[rt * 16 + l15][dh] = px;
            }
        }

        __syncthreads();                 // barrier #1: Atile init + Phi ready
#pragma unroll 1
        for (int blk = 0; blk < 8; ++blk) {
            const float dlt = dls[blk];
#pragma unroll 1
            for (int ii = 0; ii < 8; ++ii) {
                const int sub = ii & 3;
                __syncthreads();         // HsA(i)/AtileB(i) published
                DO_G2(0)                 // stream A: GEMM2 + RK4 epilogue
                __syncthreads();         // HsB(i)/AtileA(i+1) published
                DO_G2(1)                 // stream B: GEMM2 + RK4 epilogue
            }
        }
    }
#undef DO_G1
#undef DO_G2
}

extern "C" void kernel_launch(void* const* d_in, const int* in_sizes, int n_in,
                              void* d_out, int out_size, void* d_ws, size_t ws_size,
                              hipStream_t stream) {
    const float* s_in  = (const float*)d_in[0];
    const float* t_in  = (const float*)d_in[1];
    const float* phi   = (const float*)d_in[2];
    const float* bfr   = (const float*)d_in[3];
    const float* w1    = (const float*)d_in[4];
    const float* b1    = (const float*)d_in[5];
    const float* w2    = (const float*)d_in[6];
    const float* b2    = (const float*)d_in[7];
    ode_mfma<<<512, 512, 0, stream>>>(s_in, t_in, phi, bfr, w1, b1, w2, b2, (float*)d_out);
}